// Round 9
// baseline (1448.201 us; speedup 1.0000x reference)
//
#include <hip/hip_runtime.h>
#include <hip/hip_cooperative_groups.h>
#include <math.h>

namespace cg = cooperative_groups;

#define MN 1537          // M_NODES
#define NFFT 4096
#define CW 0.06283185307179587f      // 2*pi*h
#define W4096 1.5339807878856412e-3f // 2*pi/4096

__device__ __forceinline__ float2 cmulf(float2 a, float2 b) {
    return make_float2(a.x*b.x - a.y*b.y, a.x*b.y + a.y*b.x);
}
__device__ __forceinline__ float2 cadd(float2 a, float2 b){ return make_float2(a.x+b.x, a.y+b.y); }
__device__ __forceinline__ float2 csub(float2 a, float2 b){ return make_float2(a.x-b.x, a.y-b.y); }
__device__ __forceinline__ float2 mulnegi(float2 z){ return make_float2(z.y, -z.x); }  // z * (-i)
__device__ __forceinline__ float2 mulposi(float2 z){ return make_float2(-z.y, z.x); }  // z * (+i)
__device__ __forceinline__ float2 cconj(float2 z){ return make_float2(z.x, -z.y); }
// XOR bank swizzle [measured r7/r8: conflicts 8.02M -> 1.26M]
__device__ __forceinline__ int SW(int i){ return i ^ ((i >> 3) & 15); }

__device__ __forceinline__ float ws_at(int k) {
    float xi = 0.01f * (float)(k - 768);
    float t  = 0.31415926535897931f * xi;      // pi*ell*xi
    float S  = 0.25066282746310002f * expf(-2.0f * t * t); // sqrt(2pi)*ell
    return sqrtf(0.01f * S);
}

struct Tw { float2 w1, w2, w4, c1, c3; };

__device__ __forceinline__ Tw make_tw(float ang){
    Tw t;
    __sincosf(ang, &t.w1.y, &t.w1.x);
    t.w2 = cmulf(t.w1, t.w1);
    t.w4 = cmulf(t.w2, t.w2);
    const float R = 0.70710678118654752f;
    t.c1 = cmulf(t.w1, make_float2( R, -R));
    t.c3 = cmulf(t.w1, make_float2(-R, -R));
    return t;
}

// ---- forward DIF triple, wave-uniform half split (hw = wid&1): half VALU, 8r+4w
template<int S>
__device__ __forceinline__ void fwd8w(float2* fb, int bfw, int hw, const Tw& w){
    const int Q = 1 << (S-2);
    const int p = bfw & (Q-1);
    const int g = bfw >> (S-2);
    const int base = (g << (S+1)) + p;
    float2 a0 = fb[SW(base      )], a1 = fb[SW(base +   Q)];
    float2 a2 = fb[SW(base + 2*Q)], a3 = fb[SW(base + 3*Q)];
    float2 a4 = fb[SW(base + 4*Q)], a5 = fb[SW(base + 5*Q)];
    float2 a6 = fb[SW(base + 6*Q)], a7 = fb[SW(base + 7*Q)];
    if (hw == 0) {
        float2 b0 = cadd(a0,a4), b1 = cadd(a1,a5), b2 = cadd(a2,a6), b3 = cadd(a3,a7);
        float2 c0 = cadd(b0,b2), c2 = cmulf(csub(b0,b2), w.w2);
        float2 c1 = cadd(b1,b3), c3 = mulnegi(cmulf(csub(b1,b3), w.w2));
        fb[SW(base      )] = cadd(c0,c1);
        fb[SW(base +   Q)] = cmulf(csub(c0,c1), w.w4);
        fb[SW(base + 2*Q)] = cadd(c2,c3);
        fb[SW(base + 3*Q)] = cmulf(csub(c2,c3), w.w4);
    } else {
        float2 b4 = cmulf(csub(a0,a4), w.w1);
        float2 b5 = cmulf(csub(a1,a5), w.c1);
        float2 b6 = mulnegi(cmulf(csub(a2,a6), w.w1));
        float2 b7 = cmulf(csub(a3,a7), w.c3);
        float2 c4 = cadd(b4,b6), c6 = cmulf(csub(b4,b6), w.w2);
        float2 c5 = cadd(b5,b7), c7 = mulnegi(cmulf(csub(b5,b7), w.w2));
        fb[SW(base + 4*Q)] = cadd(c4,c5);
        fb[SW(base + 5*Q)] = cmulf(csub(c4,c5), w.w4);
        fb[SW(base + 6*Q)] = cadd(c6,c7);
        fb[SW(base + 7*Q)] = cmulf(csub(c6,c7), w.w4);
    }
}

// ---- inverse DIT triple, full compute, half writes (hw selects +/- outputs)
template<int S>
__device__ __forceinline__ void inv8w(float2* fb, int bfw, int hw, const Tw& w){
    const int Q = 1 << S;
    const int p = bfw & (Q-1);
    const int g = bfw >> S;
    const int base = (g << (S+3)) + p;
    float2 u1 = cconj(w.w1), u2 = cconj(w.w2), u4 = cconj(w.w4);
    float2 uc1 = cconj(w.c1), uc3 = cconj(w.c3);
    float2 a0 = fb[SW(base      )], a1 = fb[SW(base +   Q)];
    float2 a2 = fb[SW(base + 2*Q)], a3 = fb[SW(base + 3*Q)];
    float2 a4 = fb[SW(base + 4*Q)], a5 = fb[SW(base + 5*Q)];
    float2 a6 = fb[SW(base + 6*Q)], a7 = fb[SW(base + 7*Q)];
    float2 m;
    m = cmulf(a1, u4); float2 t0 = cadd(a0,m), t1 = csub(a0,m);
    m = cmulf(a3, u4); float2 t2 = cadd(a2,m), t3 = csub(a2,m);
    m = cmulf(a5, u4); float2 t4 = cadd(a4,m), t5 = csub(a4,m);
    m = cmulf(a7, u4); float2 t6 = cadd(a6,m), t7 = csub(a6,m);
    m = cmulf(t2, u2);          float2 e0 = cadd(t0,m), e2 = csub(t0,m);
    m = mulposi(cmulf(t3, u2)); float2 e1 = cadd(t1,m), e3 = csub(t1,m);
    m = cmulf(t6, u2);          float2 e4 = cadd(t4,m), e6 = csub(t4,m);
    m = mulposi(cmulf(t7, u2)); float2 e5 = cadd(t5,m), e7 = csub(t5,m);
    float2 m0 = cmulf(e4, u1);
    float2 m1 = cmulf(e5, uc1);
    float2 m2 = mulposi(cmulf(e6, u1));
    float2 m3 = cmulf(e7, uc3);
    if (hw == 0) {
        fb[SW(base      )] = cadd(e0,m0);
        fb[SW(base +   Q)] = cadd(e1,m1);
        fb[SW(base + 2*Q)] = cadd(e2,m2);
        fb[SW(base + 3*Q)] = cadd(e3,m3);
    } else {
        fb[SW(base + 4*Q)] = csub(e0,m0);
        fb[SW(base + 5*Q)] = csub(e1,m1);
        fb[SW(base + 6*Q)] = csub(e2,m2);
        fb[SW(base + 7*Q)] = csub(e3,m3);
    }
}

// ---- fused middle (fwd S=2 + pointwise*g + inv S=0), full compute, half writes
__device__ __forceinline__ void mid8w(float2* fb, int bfw, int hw, const float2* g){
    const float R = 0.70710678118654752f;
    const int base = bfw << 3;
    float2 a0 = fb[SW(base  )], a1 = fb[SW(base+1)];
    float2 a2 = fb[SW(base+2)], a3 = fb[SW(base+3)];
    float2 a4 = fb[SW(base+4)], a5 = fb[SW(base+5)];
    float2 a6 = fb[SW(base+6)], a7 = fb[SW(base+7)];
    float2 b0 = cadd(a0,a4), b1 = cadd(a1,a5), b2 = cadd(a2,a6), b3 = cadd(a3,a7);
    float2 b4 = csub(a0,a4);
    float2 b5 = cmulf(csub(a1,a5), make_float2( R, -R));
    float2 b6 = mulnegi(csub(a2,a6));
    float2 b7 = cmulf(csub(a3,a7), make_float2(-R, -R));
    float2 c0 = cadd(b0,b2), c2 = csub(b0,b2);
    float2 c1 = cadd(b1,b3), c3 = mulnegi(csub(b1,b3));
    float2 c4 = cadd(b4,b6), c6 = csub(b4,b6);
    float2 c5 = cadd(b5,b7), c7 = mulnegi(csub(b5,b7));
    float2 d0 = cadd(c0,c1), d1 = csub(c0,c1);
    float2 d2 = cadd(c2,c3), d3 = csub(c2,c3);
    float2 d4 = cadd(c4,c5), d5 = csub(c4,c5);
    float2 d6 = cadd(c6,c7), d7 = csub(c6,c7);
    d0 = cmulf(d0, g[0]); d1 = cmulf(d1, g[1]); d2 = cmulf(d2, g[2]); d3 = cmulf(d3, g[3]);
    d4 = cmulf(d4, g[4]); d5 = cmulf(d5, g[5]); d6 = cmulf(d6, g[6]); d7 = cmulf(d7, g[7]);
    float2 m;
    m = d1; float2 t0 = cadd(d0,m), t1 = csub(d0,m);
    m = d3; float2 t2 = cadd(d2,m), t3 = csub(d2,m);
    m = d5; float2 t4 = cadd(d4,m), t5 = csub(d4,m);
    m = d7; float2 t6 = cadd(d6,m), t7 = csub(d6,m);
    m = t2;          float2 e0 = cadd(t0,m), e2 = csub(t0,m);
    m = mulposi(t3); float2 e1 = cadd(t1,m), e3 = csub(t1,m);
    m = t6;          float2 e4 = cadd(t4,m), e6 = csub(t4,m);
    m = mulposi(t7); float2 e5 = cadd(t5,m), e7 = csub(t5,m);
    float2 m0 = e4;
    float2 m1 = cmulf(e5, make_float2(R, R));
    float2 m2 = mulposi(e6);
    float2 m3 = cmulf(e7, make_float2(-R, R));
    if (hw == 0) {
        fb[SW(base  )] = cadd(e0,m0);
        fb[SW(base+1)] = cadd(e1,m1);
        fb[SW(base+2)] = cadd(e2,m2);
        fb[SW(base+3)] = cadd(e3,m3);
    } else {
        fb[SW(base+4)] = csub(e0,m0);
        fb[SW(base+5)] = csub(e1,m1);
        fb[SW(base+6)] = csub(e2,m2);
        fb[SW(base+7)] = csub(e3,m3);
    }
}

// ---- G-spectrum capture: fwd S=2 triple, register outputs, full compute
__device__ __forceinline__ void fwd8_last_reg(const float2* fb, int bfw, float2* gout){
    const float R = 0.70710678118654752f;
    const int base = bfw << 3;
    float2 a0 = fb[SW(base  )], a1 = fb[SW(base+1)];
    float2 a2 = fb[SW(base+2)], a3 = fb[SW(base+3)];
    float2 a4 = fb[SW(base+4)], a5 = fb[SW(base+5)];
    float2 a6 = fb[SW(base+6)], a7 = fb[SW(base+7)];
    float2 b0 = cadd(a0,a4), b1 = cadd(a1,a5), b2 = cadd(a2,a6), b3 = cadd(a3,a7);
    float2 b4 = csub(a0,a4);
    float2 b5 = cmulf(csub(a1,a5), make_float2( R, -R));
    float2 b6 = mulnegi(csub(a2,a6));
    float2 b7 = cmulf(csub(a3,a7), make_float2(-R, -R));
    float2 c0 = cadd(b0,b2), c2 = csub(b0,b2);
    float2 c1 = cadd(b1,b3), c3 = mulnegi(csub(b1,b3));
    float2 c4 = cadd(b4,b6), c6 = csub(b4,b6);
    float2 c5 = cadd(b5,b7), c7 = mulnegi(csub(b5,b7));
    gout[0] = cadd(c0,c1); gout[1] = csub(c0,c1);
    gout[2] = cadd(c2,c3); gout[3] = csub(c2,c3);
    gout[4] = cadd(c4,c5); gout[5] = csub(c4,c5);
    gout[6] = cadd(c6,c7); gout[7] = csub(c6,c7);
}

// ---- stage-11 triple from registers; lane-pair halves (hhp = tid&1, bf = tid>>1)
// thread owns slots j0 = bf + 512*hhp, j1 = j0 + 1024; pair exchange via shfl_xor^1
__device__ __forceinline__ void fwd8_firstp(float2* fb, int bf, int hhp, const Tw& w,
                                            float2 own0, float2 own1){
    float2 r0, r1;
    r0.x = __shfl_xor(own0.x, 1, 64); r0.y = __shfl_xor(own0.y, 1, 64);
    r1.x = __shfl_xor(own1.x, 1, 64); r1.y = __shfl_xor(own1.y, 1, 64);
    float2 in0 = (hhp == 0) ? own0 : r0;   // slot bf
    float2 in1 = (hhp == 0) ? r0   : own0; // slot bf+512
    float2 in2 = (hhp == 0) ? own1 : r1;   // slot bf+1024
    float2 in3 = (hhp == 0) ? r1   : own1; // slot bf+1536
    if (hhp == 0) {
        float2 c0 = cadd(in0,in2), c2 = cmulf(csub(in0,in2), w.w2);
        float2 c1 = cadd(in1,in3), c3 = mulnegi(cmulf(csub(in1,in3), w.w2));
        fb[SW(bf       )] = cadd(c0,c1);
        fb[SW(bf +  512)] = cmulf(csub(c0,c1), w.w4);
        fb[SW(bf + 1024)] = cadd(c2,c3);
        fb[SW(bf + 1536)] = cmulf(csub(c2,c3), w.w4);
    } else {
        float2 b4 = cmulf(in0, w.w1);
        float2 b5 = cmulf(in1, w.c1);
        float2 b6 = mulnegi(cmulf(in2, w.w1));
        float2 b7 = cmulf(in3, w.c3);
        float2 c4 = cadd(b4,b6), c6 = cmulf(csub(b4,b6), w.w2);
        float2 c5 = cadd(b5,b7), c7 = mulnegi(cmulf(csub(b5,b7), w.w2));
        fb[SW(bf + 2048)] = cadd(c4,c5);
        fb[SW(bf + 2560)] = cmulf(csub(c4,c5), w.w4);
        fb[SW(bf + 3072)] = cadd(c6,c7);
        fb[SW(bf + 3584)] = cmulf(csub(c6,c7), w.w4);
    }
}

// ---- inverse stage-9 triple to registers; lane-pair halves; 4 reads/thread.
// returns cv[0] = slot j0, cv[1] = slot j1 for this thread's ownership map.
__device__ __forceinline__ void inv8_lastp(const float2* fb, int bf, int hhp, const Tw& w,
                                           float2* cv){
    float2 u1 = cconj(w.w1), u2 = cconj(w.w2), u4 = cconj(w.w4);
    float2 uc1 = cconj(w.c1), uc3 = cconj(w.c3);
    float2 ea, eb, xa, xb;
    if (hhp == 0) {
        float2 a0 = fb[SW(bf       )], a1 = fb[SW(bf +  512)];
        float2 a2 = fb[SW(bf + 1024)], a3 = fb[SW(bf + 1536)];
        float2 m;
        m = cmulf(a1, u4); float2 t0 = cadd(a0,m), t1 = csub(a0,m);
        m = cmulf(a3, u4); float2 t2 = cadd(a2,m), t3 = csub(a2,m);
        m = cmulf(t2, u2);          ea = cadd(t0,m); eb = csub(t0,m);   // e0, e2
        m = mulposi(cmulf(t3, u2)); xa = cadd(t1,m); xb = csub(t1,m);   // e1, e3 (send)
    } else {
        float2 a4 = fb[SW(bf + 2048)], a5 = fb[SW(bf + 2560)];
        float2 a6 = fb[SW(bf + 3072)], a7 = fb[SW(bf + 3584)];
        float2 m;
        m = cmulf(a5, u4); float2 t4 = cadd(a4,m), t5 = csub(a4,m);
        m = cmulf(a7, u4); float2 t6 = cadd(a6,m), t7 = csub(a6,m);
        m = cmulf(t6, u2);          float2 e4 = cadd(t4,m), e6 = csub(t4,m);
        m = mulposi(cmulf(t7, u2)); float2 e5 = cadd(t5,m), e7 = csub(t5,m);
        xa = cmulf(e4, u1);              // m0 (send)
        ea = cmulf(e5, uc1);             // m1 (keep)
        xb = mulposi(cmulf(e6, u1));     // m2 (send)
        eb = cmulf(e7, uc3);             // m3 (keep)
    }
    float2 ra, rb;
    ra.x = __shfl_xor(xa.x, 1, 64); ra.y = __shfl_xor(xa.y, 1, 64);
    rb.x = __shfl_xor(xb.x, 1, 64); rb.y = __shfl_xor(xb.y, 1, 64);
    // even: ea=e0 + ra=m0 -> slot bf;   eb=e2 + rb=m2 -> slot bf+1024
    // odd:  ra=e1 + ea=m1 -> slot bf+512; rb=e3 + eb=m3 -> slot bf+1536
    cv[0] = cadd(ea, ra);
    cv[1] = cadd(eb, rb);
}

// circular convolution; result scaled by 4096
__device__ __forceinline__ void conv_fft(float2* fb, const float2* g,
                                         int bf, int hhp, int bfw, int hw,
                                         const Tw& T11, const Tw& T8, const Tw& T5,
                                         float2 s0, float2 s1, float2* cv){
    __syncthreads();
    fwd8_firstp(fb, bf, hhp, T11, s0, s1); __syncthreads();
    fwd8w<8>(fb, bfw, hw, T8); __syncthreads();
    fwd8w<5>(fb, bfw, hw, T5); __syncthreads();
    mid8w(fb, bfw, hw, g);     __syncthreads();
    inv8w<3>(fb, bfw, hw, T5); __syncthreads();
    inv8w<6>(fb, bfw, hw, T8); __syncthreads();
    inv8_lastp(fb, bf, hhp, T11, cv);
}

// ---------------- block reductions (1024 threads = 16 waves), result to all
__device__ float block_reduce1(float v, volatile float* sc) {
    int lane = threadIdx.x & 63, wid = threadIdx.x >> 6;
    #pragma unroll
    for (int off = 32; off > 0; off >>= 1) v += __shfl_down(v, off, 64);
    if (lane == 0) sc[wid] = v;
    __syncthreads();
    if (wid == 0) {
        float s = (lane < 16) ? sc[lane] : 0.0f;
        #pragma unroll
        for (int off = 8; off > 0; off >>= 1) s += __shfl_down(s, off, 64);
        if (lane == 0) sc[16] = s;
    }
    __syncthreads();
    return sc[16];
}

__device__ float2 block_reduce2(float2 v, volatile float* sc) {
    int lane = threadIdx.x & 63, wid = threadIdx.x >> 6;
    #pragma unroll
    for (int off = 32; off > 0; off >>= 1) {
        v.x += __shfl_down(v.x, off, 64);
        v.y += __shfl_down(v.y, off, 64);
    }
    if (lane == 0) { sc[wid] = v.x; sc[20 + wid] = v.y; }
    __syncthreads();
    if (wid == 0) {
        float sx = (lane < 16) ? sc[lane] : 0.0f;
        float sy = (lane < 16) ? sc[20 + lane] : 0.0f;
        #pragma unroll
        for (int off = 8; off > 0; off >>= 1) {
            sx += __shfl_down(sx, off, 64);
            sy += __shfl_down(sy, off, 64);
        }
        if (lane == 0) { sc[16] = sx; sc[36] = sy; }
    }
    __syncthreads();
    return make_float2(sc[16], sc[36]);
}

// ======================= the cooperative mega-kernel =======================
// 128 blocks x 1024 threads (16 waves = 4/SIMD, VGPR cap 128).
// Phase S: blocks 0..63 = one Lanczos probe each; block 64 = CG.
__global__ __launch_bounds__(1024) __attribute__((amdgpu_waves_per_eu(4, 4)))
void mega(const float* __restrict__ x, const float* __restrict__ y,
          const float* __restrict__ xn, const float* __restrict__ z,
          float* __restrict__ out,
          float2* __restrict__ d_v, float2* __restrict__ d_rhs, float2* __restrict__ d_wb,
          float* __restrict__ d_al, float* __restrict__ d_be, float* __restrict__ d_nz2,
          float* __restrict__ d_quad, float* __restrict__ d_t1w)
{
    __shared__ float2 fb[NFFT];    // 32 KB
    __shared__ float  redb[40];
    cg::grid_group grid = cg::this_grid();
    const int b = blockIdx.x, tid = threadIdx.x;
    const int wid = tid >> 6, lane = tid & 63;

    // ---------------- phase P: one wave per output column
    for (int c = b*16 + wid; c < 3073 + MN; c += 2048) {
        bool is_v = c < 3073;
        float pk = is_v ? (float)(c - 1536) : (float)(c - 3073 - 768);
        float sx = 0.f, sy = 0.f;
        if (is_v){
            for (int j = 0; j < 256; ++j){
                float ph = CW * (x[j*64 + lane] * pk);
                float s, cc; __sincosf(ph, &s, &cc);
                sx += cc; sy += s;
            }
        } else {
            for (int j = 0; j < 256; ++j){
                int n = j*64 + lane;
                float yv = y[n];
                float ph = CW * (x[n] * pk);
                float s, cc; __sincosf(ph, &s, &cc);
                sx += cc*yv; sy -= s*yv;
            }
        }
        #pragma unroll
        for (int off = 32; off > 0; off >>= 1){
            sx += __shfl_down(sx, off, 64);
            sy += __shfl_down(sy, off, 64);
        }
        if (lane == 0){
            if (is_v) d_v[c] = make_float2(sx, sy);
            else      d_rhs[c - 3073] = make_float2(sx, sy);
        }
    }
    grid.sync();

    // ---------------- phase S
    if (b < 65) {
        const int bf  = tid >> 1;               // lane-pair butterfly (first/last)
        const int hhp = tid & 1;
        const int bfw = (wid >> 1)*64 + lane;   // wave-uniform butterfly (mid stages)
        const int hw  = wid & 1;
        const int j0 = bf + (hhp ? 512 : 0);
        const int j1 = j0 + 1024;
        const bool live1 = j1 < MN;
        Tw T11 = make_tw(-W4096 * (float)bf);
        Tw T8  = make_tw(-W4096 * (float)((bfw & 63) << 3));
        Tw T5  = make_tw(-W4096 * (float)((bfw & 7)  << 6));
        float w0  = ws_at(j0);
        float w1v = live1 ? ws_at(j1) : 0.f;

        // build G spectrum: g[k] = G at slot 8*bfw + k
        float2 g[8];
        {
            #pragma unroll
            for (int k = 0; k < 4; ++k){
                int i = tid + k*1024;
                float2 val = make_float2(0.f, 0.f);
                if (i == 0)            val = d_v[1536];
                else if (i <= 1536)    val = d_v[1536 - i];
                else if (i >= 2560)    val = d_v[5632 - i];
                fb[SW(i)] = val;
            }
            __syncthreads();
            Tw T11w = make_tw(-W4096 * (float)bfw);
            fwd8w<11>(fb, bfw, hw, T11w); __syncthreads();
            fwd8w<8 >(fb, bfw, hw, T8);   __syncthreads();
            fwd8w<5 >(fb, bfw, hw, T5);   __syncthreads();
            fwd8_last_reg(fb, bfw, g);
        }

        float2 cv[2];
        if (b < 64) {
            // ---------- Lanczos probe b (fused dual reduction)
            float2 q0, q1, qp0, qp1;
            float sv0, sv1 = 0.f;
            {
                float zv = z[b*MN + j0];
                sv0 = (zv > 0.f) ? 1.f : ((zv < 0.f) ? -1.f : 0.f);
            }
            if (live1){
                float zv = z[b*MN + j1];
                sv1 = (zv > 0.f) ? 1.f : ((zv < 0.f) ? -1.f : 0.f);
            }
            q0 = make_float2(sv0, 0.f); q1 = make_float2(sv1, 0.f);
            qp0 = make_float2(0.f, 0.f); qp1 = make_float2(0.f, 0.f);
            float nz2 = block_reduce1(sv0*sv0 + sv1*sv1, redb);
            if (tid == 0) d_nz2[b] = nz2;
            float qs = 1.0f / sqrtf(nz2);
            q0.x *= qs; q1.x *= qs;
            float bp = 0.f;
            const float cf0 = w0  * (10.0f / 4096.0f);
            const float cf1 = w1v * (10.0f / 4096.0f);
            for (int step = 0; step < 50; ++step) {
                float2 s0 = make_float2(w0*q0.x,  w0*q0.y);
                float2 s1 = make_float2(w1v*q1.x, w1v*q1.y);
                conv_fft(fb, g, bf, hhp, bfw, hw, T11, T8, T5, s0, s1, cv);
                float2 v0 = make_float2(q0.x + cf0*cv[0].x - bp*qp0.x,
                                        q0.y + cf0*cv[0].y - bp*qp0.y);
                float2 v1 = make_float2(q1.x + cf1*cv[1].x - bp*qp1.x,
                                        q1.y + cf1*cv[1].y - bp*qp1.y);
                float2 pp;
                pp.x = q0.x*v0.x + q0.y*v0.y + q1.x*v1.x + q1.y*v1.y;
                pp.y = v0.x*v0.x + v0.y*v0.y + v1.x*v1.x + v1.y*v1.y;
                float2 rr = block_reduce2(pp, redb);
                float alpha = rr.x;
                float beta = sqrtf(fmaxf(rr.y - alpha*alpha, 0.f));
                if (tid == 0) { d_al[b*50 + step] = alpha; d_be[b*50 + step] = beta; }
                float binv = 1.0f / fmaxf(beta, 1e-12f);
                qp0 = q0; qp1 = q1;
                q0 = make_float2((v0.x - alpha*qp0.x)*binv, (v0.y - alpha*qp0.y)*binv);
                q1 = make_float2((v1.x - alpha*qp1.x)*binv, (v1.y - alpha*qp1.y)*binv);
                bp = beta;
            }
        } else {
            // ---------- CG
            float2 r0, r1, p0, p1, x0, x1;
            {
                float2 rv = d_rhs[j0];
                r0 = make_float2(w0*rv.x, w0*rv.y);
            }
            if (live1){
                float2 rv = d_rhs[j1];
                r1 = make_float2(w1v*rv.x, w1v*rv.y);
            } else r1 = make_float2(0.f, 0.f);
            p0 = r0; p1 = r1;
            x0 = make_float2(0.f, 0.f); x1 = make_float2(0.f, 0.f);
            float rs = block_reduce1(r0.x*r0.x + r0.y*r0.y + r1.x*r1.x + r1.y*r1.y, redb);
            const float cf0 = w0  * (1.0f / 4096.0f);
            const float cf1 = w1v * (1.0f / 4096.0f);
            for (int it = 0; it < 50; ++it) {
                float2 s0 = make_float2(w0*p0.x,  w0*p0.y);
                float2 s1 = make_float2(w1v*p1.x, w1v*p1.y);
                conv_fft(fb, g, bf, hhp, bfw, hw, T11, T8, T5, s0, s1, cv);
                float2 ap0 = make_float2(cf0*cv[0].x + 0.1f*p0.x, cf0*cv[0].y + 0.1f*p0.y);
                float2 ap1 = make_float2(cf1*cv[1].x + 0.1f*p1.x, cf1*cv[1].y + 0.1f*p1.y);
                float pAp = block_reduce1(p0.x*ap0.x + p0.y*ap0.y + p1.x*ap1.x + p1.y*ap1.y, redb);
                float a = rs / pAp;
                x0.x += a*p0.x; x0.y += a*p0.y; x1.x += a*p1.x; x1.y += a*p1.y;
                r0.x -= a*ap0.x; r0.y -= a*ap0.y; r1.x -= a*ap1.x; r1.y -= a*ap1.y;
                float rsn = block_reduce1(r0.x*r0.x + r0.y*r0.y + r1.x*r1.x + r1.y*r1.y, redb);
                float sc = rsn / rs;
                p0 = make_float2(r0.x + sc*p0.x, r0.y + sc*p0.y);
                p1 = make_float2(r1.x + sc*p1.x, r1.y + sc*p1.y);
                rs = rsn;
            }
            d_wb[j0] = make_float2(w0*x0.x, w0*x0.y);
            if (live1) d_wb[j1] = make_float2(w1v*x1.x, w1v*x1.y);
        }
    }
    grid.sync();

    // ---------------- phase T: wave0 of blocks 0-63 = slq(probe b);
    // all other waves = mean rows [0,4096) + t1 rows [4096,20480), deterministic partials
    if (wid == 0 && b < 64) {
        float* sa  = (float*)fb;
        float* se  = sa + 64;
        float* se2 = sa + 128;
        int t = lane;
        if (t < 50) {
            sa[t] = d_al[b*50 + t];
            float bv = (t < 49) ? d_be[b*50 + t] : 0.0f;
            se[t] = bv; se2[t] = bv * bv;
        }
        float quad = 0.0f;
        if (t < 50) {
            float lo = 3.4e38f, hi = -3.4e38f;
            for (int i = 0; i < 50; ++i) {
                float rr = ((i > 0) ? fabsf(se[i-1]) : 0.0f) + ((i < 49) ? fabsf(se[i]) : 0.0f);
                lo = fminf(lo, sa[i] - rr);
                hi = fmaxf(hi, sa[i] + rr);
            }
            for (int it = 0; it < 38; ++it) {
                float mid = 0.5f * (lo + hi);
                int cnt = 0;
                float qq = sa[0] - mid;
                cnt += (qq < 0.0f);
                for (int k = 1; k < 50; ++k) {
                    float dnm = (fabsf(qq) < 1e-30f) ? ((qq < 0.0f) ? -1e-30f : 1e-30f) : qq;
                    qq = (sa[k] - mid) - se2[k-1] * __builtin_amdgcn_rcpf(dnm);
                    cnt += (qq < 0.0f);
                }
                if (cnt > t) hi = mid; else lo = mid;
            }
            float lam = 0.5f * (lo + hi);
            float pm = 0.0f, pc = 1.0f, s = 1.0f, bprev = 0.0f;
            for (int k = 0; k < 49; ++k) {
                float bk = fmaxf(se[k], 1e-30f);
                float pn = ((lam - sa[k]) * pc - bprev * pm) * __builtin_amdgcn_rcpf(bk);
                pn = fminf(fmaxf(pn, -1e18f), 1e18f);
                s += pn * pn;
                pm = pc; pc = pn; bprev = bk;
            }
            quad = logf(fmaxf(lam, 1e-18f)) / s;
        }
        #pragma unroll
        for (int off = 32; off > 0; off >>= 1) quad += __shfl_down(quad, off, 64);
        if (t == 0) d_quad[b] = quad * d_nz2[b];
    } else {
        int rank = (b < 64) ? (b*15 + wid - 1) : (960 + (b - 64)*16 + wid);
        float ta = 0.f;
        for (int r = rank; r < 4096 + 16384; r += 1984) {
            bool ismean = r < 4096;
            int n = ismean ? r : (r - 4096);
            float xv = ismean ? xn[n] : x[n];
            float acc = 0.f;
            for (int k = lane; k < MN; k += 64) {
                float ph = CW * (xv * (float)(k - 768));
                float s, c; __sincosf(ph, &s, &c);
                float2 ww = d_wb[k];
                acc += c * ww.x - s * ww.y;
            }
            #pragma unroll
            for (int off = 32; off > 0; off >>= 1) acc += __shfl_down(acc, off, 64);
            if (lane == 0) {
                if (ismean) out[n] = acc;
                else { float yv = y[n]; ta += yv * (yv - acc) * 10.0f; }
            }
        }
        if (lane == 0) d_t1w[rank] = ta;
    }
    grid.sync();

    // ---------------- final: lml (block 0, deterministic sums)
    if (b == 0) {
        float t1p = (tid < 1984) ? d_t1w[tid] : 0.f;
        if (tid < 960) t1p += d_t1w[tid + 1024];
        float qp2 = (tid < 64) ? d_quad[tid] : 0.f;
        float2 rr = block_reduce2(make_float2(t1p, qp2), redb);
        if (tid == 0) {
            float ld = rr.y / 64.0f - 37725.5542f;              // + N*log(sigma^2)
            out[4096] = -0.5f * rr.x - 0.5f * ld - 15055.8889f; // - 0.5*N*log(2pi)
        }
    }
}

extern "C" void kernel_launch(void* const* d_in, const int* in_sizes, int n_in,
                              void* d_out, int out_size, void* d_ws, size_t ws_size,
                              hipStream_t stream) {
    const float* d_x  = (const float*)d_in[0];
    const float* d_y  = (const float*)d_in[1];
    const float* d_xn = (const float*)d_in[2];
    const float* d_z  = (const float*)d_in[3];
    float* out = (float*)d_out;
    char* w = (char*)d_ws;
    float2* d_v   = (float2*)(w + 0);       // 3073 c64
    float2* d_rhs = (float2*)(w + 24832);   // 1537 c64
    float2* d_wb  = (float2*)(w + 37376);   // 1537 c64
    float*  d_al  = (float*)(w + 49920);    // 64x50
    float*  d_be  = (float*)(w + 62720);    // 64x50
    float*  d_nz2 = (float*)(w + 75520);    // 64
    float*  d_quad= (float*)(w + 75776);    // 64
    float*  d_t1w = (float*)(w + 76032);    // 1984 wave partials

    void* args[] = { (void*)&d_x, (void*)&d_y, (void*)&d_xn, (void*)&d_z, (void*)&out,
                     (void*)&d_v, (void*)&d_rhs, (void*)&d_wb, (void*)&d_al, (void*)&d_be,
                     (void*)&d_nz2, (void*)&d_quad, (void*)&d_t1w };
    hipLaunchCooperativeKernel((const void*)mega, dim3(128), dim3(1024), args, 0, stream);
}